// Round 1
// baseline (18827.826 us; speedup 1.0000x reference)
//
#include <hip/hip_runtime.h>

#define Hdim 128
#define Fdim 16
#define Ddim 16
#define Tdim 8
#define Bdim 2

// ---------------- encoder: x[b,n,:] = x_seq[b,t,n,:] @ enc_w + enc_b --------
__global__ __launch_bounds__(256) void enc_kernel(
    const float* __restrict__ xseq, const float* __restrict__ enc_w,
    const float* __restrict__ enc_b, float* __restrict__ x,
    int N, int t)
{
  int gid = blockIdx.x * 256 + threadIdx.x;
  int row = gid >> 5;          // b*N+n
  int q   = gid & 31;          // channel quad (4 floats)
  if (row >= Bdim * N) return;
  int b = row / N, n = row - b * N;
  const float* xs = xseq + (((size_t)b * Tdim + t) * N + n) * Fdim;
  float4 acc = ((const float4*)enc_b)[q];
#pragma unroll
  for (int f = 0; f < Fdim; ++f) {
    float s = xs[f];
    float4 w = ((const float4*)enc_w)[f * (Hdim / 4) + q];
    acc.x += s * w.x; acc.y += s * w.y; acc.z += s * w.z; acc.w += s * w.w;
  }
  ((float4*)x)[(size_t)row * (Hdim / 4) + q] = acc;
}

// ------------- edge messages: agg[b,dst,:] += relu(x[b,src,:] + e_emb) ------
__global__ __launch_bounds__(256) void msg_kernel(
    const float* __restrict__ x, float* __restrict__ agg,
    const int* __restrict__ ei, const float* __restrict__ attr,
    const float* __restrict__ eW_l, const float* __restrict__ eb_l,
    int E, int N)
{
  int gid = blockIdx.x * 256 + threadIdx.x;
  int e = gid >> 5;
  int q = gid & 31;
  if (e >= E) return;
  int b = blockIdx.y;
  int src = ei[e], dst = ei[E + e];

  const float4* a4 = (const float4*)attr + (size_t)e * 4;
  float4 A0 = a4[0], A1 = a4[1], A2 = a4[2], A3 = a4[3];
  float av[16] = {A0.x, A0.y, A0.z, A0.w, A1.x, A1.y, A1.z, A1.w,
                  A2.x, A2.y, A2.z, A2.w, A3.x, A3.y, A3.z, A3.w};

  float4 emb = ((const float4*)eb_l)[q];
#pragma unroll
  for (int d = 0; d < Ddim; ++d) {
    float4 w = ((const float4*)eW_l)[d * (Hdim / 4) + q];
    emb.x += av[d] * w.x; emb.y += av[d] * w.y;
    emb.z += av[d] * w.z; emb.w += av[d] * w.w;
  }
  float4 xv = ((const float4*)x)[((size_t)b * N + src) * (Hdim / 4) + q];
  float m0 = fmaxf(xv.x + emb.x, 0.f);
  float m1 = fmaxf(xv.y + emb.y, 0.f);
  float m2 = fmaxf(xv.z + emb.z, 0.f);
  float m3 = fmaxf(xv.w + emb.w, 0.f);
  float* ap = agg + ((size_t)b * N + dst) * Hdim + q * 4;
  atomicAdd(ap + 0, m0);
  atomicAdd(ap + 1, m1);
  atomicAdd(ap + 2, m2);
  atomicAdd(ap + 3, m3);
}

// ------- MLP (H->H relu H->H) + LayerNorm + relu + residual, 8 rows/WG ------
__global__ __launch_bounds__(128) void mlp_ln_kernel(
    float* __restrict__ x, const float* __restrict__ agg,
    const float* __restrict__ m1w, const float* __restrict__ m1b,
    const float* __restrict__ m2w, const float* __restrict__ m2b,
    const float* __restrict__ lng, const float* __restrict__ lnb)
{
  const int ROWS = 8;
  int row0 = blockIdx.x * ROWS;
  int j = threadIdx.x;
  __shared__ float sIn[ROWS][Hdim];
  __shared__ float sMid[ROWS][Hdim];
  __shared__ float red1[2], red2[2];

  float xr[ROWS];
#pragma unroll
  for (int r = 0; r < ROWS; ++r) {
    sIn[r][j] = agg[(size_t)(row0 + r) * Hdim + j];
    xr[r] = x[(size_t)(row0 + r) * Hdim + j];
  }
  __syncthreads();

  float acc[ROWS];
  float b1 = m1b[j];
#pragma unroll
  for (int r = 0; r < ROWS; ++r) acc[r] = b1;
  for (int i = 0; i < Hdim; ++i) {
    float w = m1w[i * Hdim + j];
#pragma unroll
    for (int r = 0; r < ROWS; ++r) acc[r] += sIn[r][i] * w;
  }
#pragma unroll
  for (int r = 0; r < ROWS; ++r) sMid[r][j] = fmaxf(acc[r], 0.f);
  __syncthreads();

  float b2 = m2b[j];
#pragma unroll
  for (int r = 0; r < ROWS; ++r) acc[r] = b2;
  for (int i = 0; i < Hdim; ++i) {
    float w = m2w[i * Hdim + j];
#pragma unroll
    for (int r = 0; r < ROWS; ++r) acc[r] += sMid[r][i] * w;
  }

  float gj = lng[j], bj = lnb[j];
  int wid = j >> 6, lane = j & 63;
#pragma unroll
  for (int r = 0; r < ROWS; ++r) {
    float v = acc[r];
    float s1 = v, s2 = v * v;
#pragma unroll
    for (int off = 32; off >= 1; off >>= 1) {
      s1 += __shfl_xor(s1, off);
      s2 += __shfl_xor(s2, off);
    }
    if (lane == 0) { red1[wid] = s1; red2[wid] = s2; }
    __syncthreads();
    float t1 = red1[0] + red1[1];
    float t2 = red2[0] + red2[1];
    __syncthreads();
    float mu  = t1 * (1.f / Hdim);
    float var = fmaxf(t2 * (1.f / Hdim) - mu * mu, 0.f);
    float y = (v - mu) * rsqrtf(var + 1e-5f) * gj + bj;
    x[(size_t)(row0 + r) * Hdim + j] = fmaxf(y, 0.f) + xr[r];
  }
}

// ---------------- one GRU step over all B*N rows, 8 rows/WG -----------------
__global__ __launch_bounds__(128) void gru_kernel(
    const float* __restrict__ x, float* __restrict__ hg,
    const float* __restrict__ wih, const float* __restrict__ whh,
    const float* __restrict__ bih, const float* __restrict__ bhh)
{
  const int ROWS = 8;
  int row0 = blockIdx.x * ROWS;
  int j = threadIdx.x;
  __shared__ float sX[ROWS][Hdim], sH[ROWS][Hdim];
#pragma unroll
  for (int r = 0; r < ROWS; ++r) {
    sX[r][j] = x[(size_t)(row0 + r) * Hdim + j];
    sH[r][j] = hg[(size_t)(row0 + r) * Hdim + j];
  }
  __syncthreads();

  float air[ROWS], aiz[ROWS], ain[ROWS], ahr[ROWS], ahz[ROWS], ahn[ROWS];
  float bir = bih[j], biz = bih[Hdim + j], bin_ = bih[2 * Hdim + j];
  float bhr = bhh[j], bhz = bhh[Hdim + j], bhn = bhh[2 * Hdim + j];
#pragma unroll
  for (int r = 0; r < ROWS; ++r) {
    air[r] = bir; aiz[r] = biz; ain[r] = bin_;
    ahr[r] = bhr; ahz[r] = bhz; ahn[r] = bhn;
  }
  for (int i = 0; i < Hdim; ++i) {
    float wir = wih[i * 384 + j], wiz = wih[i * 384 + 128 + j], win = wih[i * 384 + 256 + j];
    float whr = whh[i * 384 + j], whz = whh[i * 384 + 128 + j], whn = whh[i * 384 + 256 + j];
#pragma unroll
    for (int r = 0; r < ROWS; ++r) {
      float xv = sX[r][i], hv = sH[r][i];
      air[r] += xv * wir; aiz[r] += xv * wiz; ain[r] += xv * win;
      ahr[r] += hv * whr; ahz[r] += hv * whz; ahn[r] += hv * whn;
    }
  }
#pragma unroll
  for (int r = 0; r < ROWS; ++r) {
    float rr = 1.f / (1.f + expf(-(air[r] + ahr[r])));
    float zz = 1.f / (1.f + expf(-(aiz[r] + ahz[r])));
    float nn = tanhf(ain[r] + rr * ahn[r]);
    float hold = sH[r][j];
    hg[(size_t)(row0 + r) * Hdim + j] = (1.f - zz) * nn + zz * hold;
  }
}

// ---------------- head: out[row] = dot(h[row], head_w) + head_b -------------
__global__ __launch_bounds__(128) void head_kernel(
    const float* __restrict__ hg, const float* __restrict__ hw,
    const float* __restrict__ hb, float* __restrict__ out)
{
  int row = blockIdx.x;
  int j = threadIdx.x;
  __shared__ float red[2];
  float v = hg[(size_t)row * Hdim + j] * hw[j];
#pragma unroll
  for (int off = 32; off >= 1; off >>= 1) v += __shfl_xor(v, off);
  int wid = j >> 6, lane = j & 63;
  if (lane == 0) red[wid] = v;
  __syncthreads();
  if (j == 0) out[row] = red[0] + red[1] + hb[0];
}

extern "C" void kernel_launch(void* const* d_in, const int* in_sizes, int n_in,
                              void* d_out, int out_size, void* d_ws, size_t ws_size,
                              hipStream_t stream)
{
  const float* xseq  = (const float*)d_in[0];
  const int*   ei    = (const int*)d_in[1];
  const float* attr  = (const float*)d_in[2];
  const float* enc_w = (const float*)d_in[3];
  const float* enc_b = (const float*)d_in[4];
  const float* eW    = (const float*)d_in[5];
  const float* eb    = (const float*)d_in[6];
  const float* m1w   = (const float*)d_in[7];
  const float* m1b   = (const float*)d_in[8];
  const float* m2w   = (const float*)d_in[9];
  const float* m2b   = (const float*)d_in[10];
  const float* lng   = (const float*)d_in[11];
  const float* lnb   = (const float*)d_in[12];
  const float* wih   = (const float*)d_in[13];
  const float* whh   = (const float*)d_in[14];
  const float* bih   = (const float*)d_in[15];
  const float* bhh   = (const float*)d_in[16];
  const float* hw    = (const float*)d_in[17];
  const float* hb    = (const float*)d_in[18];

  int E = in_sizes[1] / 2;
  int N = in_sizes[0] / (Bdim * Tdim * Fdim);
  int rows = Bdim * N;
  size_t S = (size_t)rows * Hdim;   // floats per [B*N, H] buffer

  float* x   = (float*)d_ws;
  float* agg = x + S;
  float* hgb = agg + S;

  hipMemsetAsync(hgb, 0, S * sizeof(float), stream);

  int encBlocks = (rows * 32 + 255) / 256;
  int msgBlocks = (E * 32 + 255) / 256;
  int rowBlocks = rows / 8;   // 20000/8 = 2500

  for (int t = 0; t < Tdim; ++t) {
    enc_kernel<<<encBlocks, 256, 0, stream>>>(xseq, enc_w, enc_b, x, N, t);
    for (int l = 0; l < 2; ++l) {
      hipMemcpyAsync(agg, x, S * sizeof(float), hipMemcpyDeviceToDevice, stream);
      msg_kernel<<<dim3(msgBlocks, Bdim), 256, 0, stream>>>(
          x, agg, ei, attr, eW + (size_t)l * Ddim * Hdim, eb + (size_t)l * Hdim, E, N);
      mlp_ln_kernel<<<rowBlocks, 128, 0, stream>>>(
          x, agg, m1w + (size_t)l * Hdim * Hdim, m1b + (size_t)l * Hdim,
          m2w + (size_t)l * Hdim * Hdim, m2b + (size_t)l * Hdim,
          lng + (size_t)l * Hdim, lnb + (size_t)l * Hdim);
    }
    gru_kernel<<<rowBlocks, 128, 0, stream>>>(x, hgb, wih, whh, bih, bhh);
  }
  head_kernel<<<rows, 128, 0, stream>>>(hgb, hw, hb, (float*)d_out);
}

// Round 2
// 2591.385 us; speedup vs baseline: 7.2655x; 7.2655x over previous
//
#include <hip/hip_runtime.h>

#define Hdim 128
#define Fdim 16
#define Ddim 16
#define Tdim 8
#define Bdim 2

// ---------------- encoder: x[b,n,:] = x_seq[b,t,n,:] @ enc_w + enc_b --------
__global__ __launch_bounds__(256) void enc_kernel(
    const float* __restrict__ xseq, const float* __restrict__ enc_w,
    const float* __restrict__ enc_b, float* __restrict__ x,
    int N, int t)
{
  int gid = blockIdx.x * 256 + threadIdx.x;
  int row = gid >> 5;          // b*N+n
  int q   = gid & 31;          // channel quad (4 floats)
  if (row >= Bdim * N) return;
  int b = row / N, n = row - b * N;
  const float* xs = xseq + (((size_t)b * Tdim + t) * N + n) * Fdim;
  float4 acc = ((const float4*)enc_b)[q];
#pragma unroll
  for (int f = 0; f < Fdim; ++f) {
    float s = xs[f];
    float4 w = ((const float4*)enc_w)[f * (Hdim / 4) + q];
    acc.x += s * w.x; acc.y += s * w.y; acc.z += s * w.z; acc.w += s * w.w;
  }
  ((float4*)x)[(size_t)row * (Hdim / 4) + q] = acc;
}

// ---------------- CSR build: count, scan, fill ------------------------------
__global__ __launch_bounds__(256) void count_kernel(
    const int* __restrict__ ei, int* __restrict__ cnt, int E)
{
  int e = blockIdx.x * 256 + threadIdx.x;
  if (e < E) atomicAdd(&cnt[ei[E + e]], 1);
}

__global__ __launch_bounds__(1024) void scan_kernel(
    const int* __restrict__ cnt, int* __restrict__ off, int N)
{
  __shared__ int part[1024];
  int tid = threadIdx.x;
  int per = (N + 1023) / 1024;
  int base = tid * per;
  int s = 0;
  for (int i = 0; i < per; ++i) { int idx = base + i; if (idx < N) s += cnt[idx]; }
  part[tid] = s;
  __syncthreads();
  for (int d = 1; d < 1024; d <<= 1) {
    int v = (tid >= d) ? part[tid - d] : 0;
    __syncthreads();
    part[tid] += v;
    __syncthreads();
  }
  int run = (tid == 0) ? 0 : part[tid - 1];
  for (int i = 0; i < per; ++i) {
    int idx = base + i;
    if (idx < N) { off[idx] = run; run += cnt[idx]; }
  }
  if (tid == 1023) off[N] = part[1023];
}

// fill uses off itself as cursor; afterwards off[d] == start(d+1)
__global__ __launch_bounds__(256) void fill_kernel(
    const int* __restrict__ ei, int* __restrict__ off,
    int* __restrict__ eids, int E)
{
  int e = blockIdx.x * 256 + threadIdx.x;
  if (e < E) {
    int d = ei[E + e];
    int pos = atomicAdd(&off[d], 1);
    eids[pos] = e;
  }
}

// ---- pull aggregation: agg[b,n,:] = x[b,n,:] + sum_{e->n} relu(x[b,src]+emb_e)
// one wave per node, both batches; eW column quad held in registers
__global__ __launch_bounds__(256) void pull_kernel(
    const float* __restrict__ x, float* __restrict__ agg,
    const int* __restrict__ ei, const int* __restrict__ off,
    const int* __restrict__ eids, const float* __restrict__ attr,
    const float* __restrict__ eW_l, const float* __restrict__ eb_l,
    int E, int N)
{
  int tid = threadIdx.x;
  int wave = tid >> 6;
  int lane = tid & 63;
  int q = lane & 31;         // channel quad
  int eslot = lane >> 5;     // which of 2 edges in flight
  int node = blockIdx.x * 4 + wave;
  if (node >= N) return;

  // weights for this lane's column quad, in registers (16 float4 = 64 VGPR)
  float4 w[16];
#pragma unroll
  for (int d = 0; d < 16; ++d) w[d] = ((const float4*)eW_l)[d * 32 + q];
  float4 bq = ((const float4*)eb_l)[q];

  int start = (node == 0) ? 0 : off[node - 1];   // off was shifted by fill
  int end = off[node];

  const float4* x4 = (const float4*)x;
  float4 a0 = {0.f, 0.f, 0.f, 0.f}, a1 = {0.f, 0.f, 0.f, 0.f};

  for (int i = start + eslot; i < end; i += 2) {
    int e = eids[i];
    int src = ei[e];
    const float4* av4 = (const float4*)(attr + (size_t)e * 16);
    float4 A0 = av4[0], A1 = av4[1], A2 = av4[2], A3 = av4[3];
    float4 emb = bq;
#define EMB_FMA(Acomp, widx) \
    emb.x += Acomp * w[widx].x; emb.y += Acomp * w[widx].y; \
    emb.z += Acomp * w[widx].z; emb.w += Acomp * w[widx].w;
    EMB_FMA(A0.x, 0)  EMB_FMA(A0.y, 1)  EMB_FMA(A0.z, 2)  EMB_FMA(A0.w, 3)
    EMB_FMA(A1.x, 4)  EMB_FMA(A1.y, 5)  EMB_FMA(A1.z, 6)  EMB_FMA(A1.w, 7)
    EMB_FMA(A2.x, 8)  EMB_FMA(A2.y, 9)  EMB_FMA(A2.z, 10) EMB_FMA(A2.w, 11)
    EMB_FMA(A3.x, 12) EMB_FMA(A3.y, 13) EMB_FMA(A3.z, 14) EMB_FMA(A3.w, 15)
#undef EMB_FMA
    float4 xv0 = x4[(size_t)src * 32 + q];
    float4 xv1 = x4[((size_t)N + src) * 32 + q];
    a0.x += fmaxf(xv0.x + emb.x, 0.f); a0.y += fmaxf(xv0.y + emb.y, 0.f);
    a0.z += fmaxf(xv0.z + emb.z, 0.f); a0.w += fmaxf(xv0.w + emb.w, 0.f);
    a1.x += fmaxf(xv1.x + emb.x, 0.f); a1.y += fmaxf(xv1.y + emb.y, 0.f);
    a1.z += fmaxf(xv1.z + emb.z, 0.f); a1.w += fmaxf(xv1.w + emb.w, 0.f);
  }
  // combine the two edge slots (lane ^ 32)
  a0.x += __shfl_xor(a0.x, 32); a0.y += __shfl_xor(a0.y, 32);
  a0.z += __shfl_xor(a0.z, 32); a0.w += __shfl_xor(a0.w, 32);
  a1.x += __shfl_xor(a1.x, 32); a1.y += __shfl_xor(a1.y, 32);
  a1.z += __shfl_xor(a1.z, 32); a1.w += __shfl_xor(a1.w, 32);

  if (eslot == 0) {
    float4 s0 = x4[(size_t)node * 32 + q];
    float4 s1 = x4[((size_t)N + node) * 32 + q];
    float4 o0 = {a0.x + s0.x, a0.y + s0.y, a0.z + s0.z, a0.w + s0.w};
    float4 o1 = {a1.x + s1.x, a1.y + s1.y, a1.z + s1.z, a1.w + s1.w};
    ((float4*)agg)[(size_t)node * 32 + q] = o0;
    ((float4*)agg)[((size_t)N + node) * 32 + q] = o1;
  }
}

// ------- MLP (H->H relu H->H) + LayerNorm + relu + residual, 8 rows/WG ------
__global__ __launch_bounds__(128) void mlp_ln_kernel(
    float* __restrict__ x, const float* __restrict__ agg,
    const float* __restrict__ m1w, const float* __restrict__ m1b,
    const float* __restrict__ m2w, const float* __restrict__ m2b,
    const float* __restrict__ lng, const float* __restrict__ lnb)
{
  const int ROWS = 8;
  int row0 = blockIdx.x * ROWS;
  int j = threadIdx.x;
  __shared__ float sIn[ROWS][Hdim];
  __shared__ float sMid[ROWS][Hdim];
  __shared__ float red1[2], red2[2];

  float xr[ROWS];
#pragma unroll
  for (int r = 0; r < ROWS; ++r) {
    sIn[r][j] = agg[(size_t)(row0 + r) * Hdim + j];
    xr[r] = x[(size_t)(row0 + r) * Hdim + j];
  }
  __syncthreads();

  float acc[ROWS];
  float b1 = m1b[j];
#pragma unroll
  for (int r = 0; r < ROWS; ++r) acc[r] = b1;
  for (int i = 0; i < Hdim; ++i) {
    float w = m1w[i * Hdim + j];
#pragma unroll
    for (int r = 0; r < ROWS; ++r) acc[r] += sIn[r][i] * w;
  }
#pragma unroll
  for (int r = 0; r < ROWS; ++r) sMid[r][j] = fmaxf(acc[r], 0.f);
  __syncthreads();

  float b2 = m2b[j];
#pragma unroll
  for (int r = 0; r < ROWS; ++r) acc[r] = b2;
  for (int i = 0; i < Hdim; ++i) {
    float w = m2w[i * Hdim + j];
#pragma unroll
    for (int r = 0; r < ROWS; ++r) acc[r] += sMid[r][i] * w;
  }

  float gj = lng[j], bj = lnb[j];
  int wid = j >> 6, lane = j & 63;
#pragma unroll
  for (int r = 0; r < ROWS; ++r) {
    float v = acc[r];
    float s1 = v, s2 = v * v;
#pragma unroll
    for (int off = 32; off >= 1; off >>= 1) {
      s1 += __shfl_xor(s1, off);
      s2 += __shfl_xor(s2, off);
    }
    if (lane == 0) { red1[wid] = s1; red2[wid] = s2; }
    __syncthreads();
    float t1 = red1[0] + red1[1];
    float t2 = red2[0] + red2[1];
    __syncthreads();
    float mu  = t1 * (1.f / Hdim);
    float var = fmaxf(t2 * (1.f / Hdim) - mu * mu, 0.f);
    float y = (v - mu) * rsqrtf(var + 1e-5f) * gj + bj;
    x[(size_t)(row0 + r) * Hdim + j] = fmaxf(y, 0.f) + xr[r];
  }
}

// ---------------- one GRU step over all B*N rows, 8 rows/WG -----------------
__global__ __launch_bounds__(128) void gru_kernel(
    const float* __restrict__ x, float* __restrict__ hg,
    const float* __restrict__ wih, const float* __restrict__ whh,
    const float* __restrict__ bih, const float* __restrict__ bhh)
{
  const int ROWS = 8;
  int row0 = blockIdx.x * ROWS;
  int j = threadIdx.x;
  __shared__ float sX[ROWS][Hdim], sH[ROWS][Hdim];
#pragma unroll
  for (int r = 0; r < ROWS; ++r) {
    sX[r][j] = x[(size_t)(row0 + r) * Hdim + j];
    sH[r][j] = hg[(size_t)(row0 + r) * Hdim + j];
  }
  __syncthreads();

  float air[ROWS], aiz[ROWS], ain[ROWS], ahr[ROWS], ahz[ROWS], ahn[ROWS];
  float bir = bih[j], biz = bih[Hdim + j], bin_ = bih[2 * Hdim + j];
  float bhr = bhh[j], bhz = bhh[Hdim + j], bhn = bhh[2 * Hdim + j];
#pragma unroll
  for (int r = 0; r < ROWS; ++r) {
    air[r] = bir; aiz[r] = biz; ain[r] = bin_;
    ahr[r] = bhr; ahz[r] = bhz; ahn[r] = bhn;
  }
  for (int i = 0; i < Hdim; ++i) {
    float wir = wih[i * 384 + j], wiz = wih[i * 384 + 128 + j], win = wih[i * 384 + 256 + j];
    float whr = whh[i * 384 + j], whz = whh[i * 384 + 128 + j], whn = whh[i * 384 + 256 + j];
#pragma unroll
    for (int r = 0; r < ROWS; ++r) {
      float xv = sX[r][i], hv = sH[r][i];
      air[r] += xv * wir; aiz[r] += xv * wiz; ain[r] += xv * win;
      ahr[r] += hv * whr; ahz[r] += hv * whz; ahn[r] += hv * whn;
    }
  }
#pragma unroll
  for (int r = 0; r < ROWS; ++r) {
    float rr = 1.f / (1.f + expf(-(air[r] + ahr[r])));
    float zz = 1.f / (1.f + expf(-(aiz[r] + ahz[r])));
    float nn = tanhf(ain[r] + rr * ahn[r]);
    float hold = sH[r][j];
    hg[(size_t)(row0 + r) * Hdim + j] = (1.f - zz) * nn + zz * hold;
  }
}

// ---------------- head: out[row] = dot(h[row], head_w) + head_b -------------
__global__ __launch_bounds__(128) void head_kernel(
    const float* __restrict__ hg, const float* __restrict__ hw,
    const float* __restrict__ hb, float* __restrict__ out)
{
  int row = blockIdx.x;
  int j = threadIdx.x;
  __shared__ float red[2];
  float v = hg[(size_t)row * Hdim + j] * hw[j];
#pragma unroll
  for (int off = 32; off >= 1; off >>= 1) v += __shfl_xor(v, off);
  int wid = j >> 6, lane = j & 63;
  if (lane == 0) red[wid] = v;
  __syncthreads();
  if (j == 0) out[row] = red[0] + red[1] + hb[0];
}

extern "C" void kernel_launch(void* const* d_in, const int* in_sizes, int n_in,
                              void* d_out, int out_size, void* d_ws, size_t ws_size,
                              hipStream_t stream)
{
  const float* xseq  = (const float*)d_in[0];
  const int*   ei    = (const int*)d_in[1];
  const float* attr  = (const float*)d_in[2];
  const float* enc_w = (const float*)d_in[3];
  const float* enc_b = (const float*)d_in[4];
  const float* eW    = (const float*)d_in[5];
  const float* eb    = (const float*)d_in[6];
  const float* m1w   = (const float*)d_in[7];
  const float* m1b   = (const float*)d_in[8];
  const float* m2w   = (const float*)d_in[9];
  const float* m2b   = (const float*)d_in[10];
  const float* lng   = (const float*)d_in[11];
  const float* lnb   = (const float*)d_in[12];
  const float* wih   = (const float*)d_in[13];
  const float* whh   = (const float*)d_in[14];
  const float* bih   = (const float*)d_in[15];
  const float* bhh   = (const float*)d_in[16];
  const float* hw    = (const float*)d_in[17];
  const float* hb    = (const float*)d_in[18];

  int E = in_sizes[1] / 2;
  int N = in_sizes[0] / (Bdim * Tdim * Fdim);
  int rows = Bdim * N;
  size_t S = (size_t)rows * Hdim;   // floats per [B*N, H] buffer

  float* x   = (float*)d_ws;
  float* agg = x + S;
  float* hgb = agg + S;
  int*   cnt  = (int*)(hgb + S);
  int*   off  = cnt + N;
  int*   eids = off + (N + 1);

  hipMemsetAsync(hgb, 0, S * sizeof(float), stream);
  hipMemsetAsync(cnt, 0, N * sizeof(int), stream);

  int eBlocks   = (E + 255) / 256;
  int encBlocks = (rows * 32 + 255) / 256;
  int rowBlocks = rows / 8;        // 20000/8 = 2500
  int pullBlocks = (N + 3) / 4;    // one wave per node

  count_kernel<<<eBlocks, 256, 0, stream>>>(ei, cnt, E);
  scan_kernel<<<1, 1024, 0, stream>>>(cnt, off, N);
  fill_kernel<<<eBlocks, 256, 0, stream>>>(ei, off, eids, E);

  for (int t = 0; t < Tdim; ++t) {
    enc_kernel<<<encBlocks, 256, 0, stream>>>(xseq, enc_w, enc_b, x, N, t);
    for (int l = 0; l < 2; ++l) {
      pull_kernel<<<pullBlocks, 256, 0, stream>>>(
          x, agg, ei, off, eids, attr,
          eW + (size_t)l * Ddim * Hdim, eb + (size_t)l * Hdim, E, N);
      mlp_ln_kernel<<<rowBlocks, 128, 0, stream>>>(
          x, agg, m1w + (size_t)l * Hdim * Hdim, m1b + (size_t)l * Hdim,
          m2w + (size_t)l * Hdim * Hdim, m2b + (size_t)l * Hdim,
          lng + (size_t)l * Hdim, lnb + (size_t)l * Hdim);
    }
    gru_kernel<<<rowBlocks, 128, 0, stream>>>(x, hgb, wih, whh, bih, bhh);
  }
  head_kernel<<<rows, 128, 0, stream>>>(hgb, hw, hb, (float*)d_out);
}

// Round 5
// 2456.868 us; speedup vs baseline: 7.6633x; 1.0548x over previous
//
#include <hip/hip_runtime.h>

#define Hdim 128
#define Fdim 16
#define Ddim 16
#define Tdim 8
#define Bdim 2
#define TC 4          // timesteps per chunk (2 chunks)

// row layout inside a chunk: flat row = ((tin*N + n)*Bdim + b), H floats each

// ---------------- encoder for one chunk -------------------------------------
__global__ __launch_bounds__(256) void enc_kernel(
    const float* __restrict__ xseq, const float* __restrict__ enc_w,
    const float* __restrict__ enc_b, float* __restrict__ x,
    int N, int t0)
{
  int gid = blockIdx.x * 256 + threadIdx.x;
  int row = gid >> 5;          // flat chunk row
  int q   = gid & 31;          // channel quad
  int rowsC = TC * Bdim * N;
  if (row >= rowsC) return;
  int b  = row & 1;
  int rn = row >> 1;
  int tin = rn / N, n = rn - tin * N;
  const float* xs = xseq + (((size_t)b * Tdim + (t0 + tin)) * N + n) * Fdim;
  float4 acc = ((const float4*)enc_b)[q];
#pragma unroll
  for (int f = 0; f < Fdim; ++f) {
    float s = xs[f];
    float4 w = ((const float4*)enc_w)[f * (Hdim / 4) + q];
    acc.x += s * w.x; acc.y += s * w.y; acc.z += s * w.z; acc.w += s * w.w;
  }
  ((float4*)x)[(size_t)row * (Hdim / 4) + q] = acc;
}

// ---------------- CSR build: count, scan, fill ------------------------------
__global__ __launch_bounds__(256) void count_kernel(
    const int* __restrict__ ei, int* __restrict__ cnt, int E)
{
  int e = blockIdx.x * 256 + threadIdx.x;
  if (e < E) atomicAdd(&cnt[ei[E + e]], 1);
}

__global__ __launch_bounds__(1024) void scan_kernel(
    const int* __restrict__ cnt, int* __restrict__ off, int N)
{
  __shared__ int part[1024];
  int tid = threadIdx.x;
  int per = (N + 1023) / 1024;
  int base = tid * per;
  int s = 0;
  for (int i = 0; i < per; ++i) { int idx = base + i; if (idx < N) s += cnt[idx]; }
  part[tid] = s;
  __syncthreads();
  for (int d = 1; d < 1024; d <<= 1) {
    int v = (tid >= d) ? part[tid - d] : 0;
    __syncthreads();
    part[tid] += v;
    __syncthreads();
  }
  int run = (tid == 0) ? 0 : part[tid - 1];
  for (int i = 0; i < per; ++i) {
    int idx = base + i;
    if (idx < N) { off[idx] = run; run += cnt[idx]; }
  }
  if (tid == 1023) off[N] = part[1023];
}

// fill uses off itself as cursor; afterwards off[d] == start(d+1)
__global__ __launch_bounds__(256) void fill_kernel(
    const int* __restrict__ ei, int* __restrict__ off,
    int* __restrict__ eids, int* __restrict__ src_csr, int E)
{
  int e = blockIdx.x * 256 + threadIdx.x;
  if (e < E) {
    int d = ei[E + e];
    int pos = atomicAdd(&off[d], 1);
    eids[pos] = e;
    src_csr[pos] = ei[e];
  }
}

// ---------------- reorder attr into CSR slot order (fp32, exact) ------------
__global__ __launch_bounds__(256) void reorder_kernel(
    const float* __restrict__ attr, const int* __restrict__ eids,
    float* __restrict__ attr_csr, int E)
{
  int gid = blockIdx.x * 256 + threadIdx.x;
  int slot = gid >> 2, q = gid & 3;
  if (slot >= E) return;
  int e = eids[slot];
  ((float4*)attr_csr)[(size_t)slot * 4 + q] =
      ((const float4*)attr)[(size_t)e * 4 + q];
}

// ---- pull: one wave per node, all TC timesteps x 2 batches -----------------
// lane c owns channels {2c,2c+1}; edge scalars (src, attr) are wave-uniform.
__global__ __launch_bounds__(256) void pull_kernel(
    const float* __restrict__ x, float* __restrict__ agg,
    const int* __restrict__ src_csr, const int* __restrict__ off,
    const float* __restrict__ attr_csr,
    const float* __restrict__ eW_l, const float* __restrict__ eb_l,
    int N)
{
  int node = __builtin_amdgcn_readfirstlane(
      blockIdx.x * 4 + (threadIdx.x >> 6));
  if (node >= N) return;
  int c = threadIdx.x & 63;

  float2 w[16];
#pragma unroll
  for (int d = 0; d < 16; ++d) w[d] = ((const float2*)eW_l)[d * 64 + c];
  float2 bq = ((const float2*)eb_l)[c];

  int start = (node == 0) ? 0 : off[node - 1];
  int end   = off[node];

  float2 acc[TC][Bdim];
#pragma unroll
  for (int t = 0; t < TC; ++t)
#pragma unroll
    for (int b = 0; b < Bdim; ++b) { acc[t][b].x = 0.f; acc[t][b].y = 0.f; }

  const float2* x2 = (const float2*)x;

  for (int i = start; i < end; ++i) {
    int src = src_csr[i];                      // s_load (uniform)
    const float* av = attr_csr + (size_t)i * 16;
    float2 e = bq;
#pragma unroll
    for (int d = 0; d < 16; ++d) {
      float a = av[d];                         // s_load (uniform)
      e.x += a * w[d].x; e.y += a * w[d].y;
    }
#pragma unroll
    for (int t = 0; t < TC; ++t) {
#pragma unroll
      for (int b = 0; b < Bdim; ++b) {
        float2 xv = x2[(size_t)((t * N + src) * Bdim + b) * 64 + c];
        acc[t][b].x += fmaxf(xv.x + e.x, 0.f);
        acc[t][b].y += fmaxf(xv.y + e.y, 0.f);
      }
    }
  }

#pragma unroll
  for (int t = 0; t < TC; ++t) {
#pragma unroll
    for (int b = 0; b < Bdim; ++b) {
      size_t row = (size_t)((t * N + node) * Bdim + b);
      float2 s = x2[row * 64 + c];
      float2 o = {acc[t][b].x + s.x, acc[t][b].y + s.y};
      ((float2*)agg)[row * 64 + c] = o;
    }
  }
}

// ------- MLP (H->H relu H->H) + LayerNorm + relu + residual, 16 rows/WG -----
// race-free: each thread reads/writes only its own (row, j) element of x.
__global__ __launch_bounds__(128) void mlp_ln_kernel(
    float* __restrict__ x, const float* __restrict__ agg,
    const float* __restrict__ m1w, const float* __restrict__ m1b,
    const float* __restrict__ m2w, const float* __restrict__ m2b,
    const float* __restrict__ lng, const float* __restrict__ lnb)
{
  const int ROWS = 16;
  int row0 = blockIdx.x * ROWS;
  int j = threadIdx.x;
  __shared__ float sMid[ROWS][Hdim];
  __shared__ float red1[2], red2[2];

  float xr[ROWS];
#pragma unroll
  for (int r = 0; r < ROWS; ++r) xr[r] = x[(size_t)(row0 + r) * Hdim + j];

  const float4* agg4 = (const float4*)agg;
  float acc[ROWS];
  float b1 = m1b[j];
#pragma unroll
  for (int r = 0; r < ROWS; ++r) acc[r] = b1;
  for (int i4 = 0; i4 < Hdim / 4; ++i4) {
    float w0 = m1w[(i4 * 4 + 0) * Hdim + j];
    float w1 = m1w[(i4 * 4 + 1) * Hdim + j];
    float w2 = m1w[(i4 * 4 + 2) * Hdim + j];
    float w3 = m1w[(i4 * 4 + 3) * Hdim + j];
#pragma unroll
    for (int r = 0; r < ROWS; ++r) {
      float4 av = agg4[(size_t)(row0 + r) * 32 + i4];   // uniform -> broadcast
      acc[r] += av.x * w0 + av.y * w1 + av.z * w2 + av.w * w3;
    }
  }
#pragma unroll
  for (int r = 0; r < ROWS; ++r) sMid[r][j] = fmaxf(acc[r], 0.f);
  __syncthreads();

  float b2 = m2b[j];
#pragma unroll
  for (int r = 0; r < ROWS; ++r) acc[r] = b2;
  for (int i4 = 0; i4 < Hdim / 4; ++i4) {
    float w0 = m2w[(i4 * 4 + 0) * Hdim + j];
    float w1 = m2w[(i4 * 4 + 1) * Hdim + j];
    float w2 = m2w[(i4 * 4 + 2) * Hdim + j];
    float w3 = m2w[(i4 * 4 + 3) * Hdim + j];
#pragma unroll
    for (int r = 0; r < ROWS; ++r) {
      float4 mv = *(const float4*)&sMid[r][i4 * 4];
      acc[r] += mv.x * w0 + mv.y * w1 + mv.z * w2 + mv.w * w3;
    }
  }

  float gj = lng[j], bj = lnb[j];
  int wid = j >> 6, lane = j & 63;
#pragma unroll
  for (int r = 0; r < ROWS; ++r) {
    float v = acc[r];
    float s1 = v, s2 = v * v;
#pragma unroll
    for (int off = 32; off >= 1; off >>= 1) {
      s1 += __shfl_xor(s1, off);
      s2 += __shfl_xor(s2, off);
    }
    if (lane == 0) { red1[wid] = s1; red2[wid] = s2; }
    __syncthreads();
    float t1 = red1[0] + red1[1];
    float t2 = red2[0] + red2[1];
    __syncthreads();
    float mu  = t1 * (1.f / Hdim);
    float var = fmaxf(t2 * (1.f / Hdim) - mu * mu, 0.f);
    float y = (v - mu) * rsqrtf(var + 1e-5f) * gj + bj;
    x[(size_t)(row0 + r) * Hdim + j] = fmaxf(y, 0.f) + xr[r];
  }
}

// ---------------- one GRU step, 16 rows/WG ----------------------------------
// state rows are (b*N+n); x rows are ((tin*N+n)*Bdim+b) in the chunk buffer.
// RACE FIX (r4->r5): GEMM phase reads ALL channels of hg rows owned by this
// block; write phase overwrites them. Without a barrier, wave 0's writes can
// land while wave 1 is still reading -> corrupted recurrent state (the r3/r4
// 0.1 absmax failures). __syncthreads() orders read phase before write phase;
// rows are block-private so a workgroup barrier is sufficient.
__global__ __launch_bounds__(128, 2) void gru_kernel(
    const float* __restrict__ x, float* __restrict__ hg,
    const float* __restrict__ wih, const float* __restrict__ whh,
    const float* __restrict__ bih, const float* __restrict__ bhh,
    int N, int tin)
{
  const int ROWS = 16;
  int row0 = blockIdx.x * ROWS;
  int j = threadIdx.x;

  int xrow[ROWS];
#pragma unroll
  for (int r = 0; r < ROWS; ++r) {
    int rr = row0 + r;
    int b = rr / N, n = rr - b * N;
    xrow[r] = (tin * N + n) * Bdim + b;
  }

  float air[ROWS], aiz[ROWS], ain[ROWS], ahr[ROWS], ahz[ROWS], ahn[ROWS];
  float bir = bih[j], biz = bih[Hdim + j], bin_ = bih[2 * Hdim + j];
  float bhr = bhh[j], bhz = bhh[Hdim + j], bhn = bhh[2 * Hdim + j];
#pragma unroll
  for (int r = 0; r < ROWS; ++r) {
    air[r] = bir; aiz[r] = biz; ain[r] = bin_;
    ahr[r] = bhr; ahz[r] = bhz; ahn[r] = bhn;
  }

  const float2* x2 = (const float2*)x;
  const float2* h2 = (const float2*)hg;
  for (int i2 = 0; i2 < Hdim / 2; ++i2) {
    int i = i2 * 2;
    float w0a = wih[(i + 0) * 384 + j], w0b = wih[(i + 0) * 384 + 128 + j], w0c = wih[(i + 0) * 384 + 256 + j];
    float w1a = wih[(i + 1) * 384 + j], w1b = wih[(i + 1) * 384 + 128 + j], w1c = wih[(i + 1) * 384 + 256 + j];
    float v0a = whh[(i + 0) * 384 + j], v0b = whh[(i + 0) * 384 + 128 + j], v0c = whh[(i + 0) * 384 + 256 + j];
    float v1a = whh[(i + 1) * 384 + j], v1b = whh[(i + 1) * 384 + 128 + j], v1c = whh[(i + 1) * 384 + 256 + j];
#pragma unroll
    for (int r = 0; r < ROWS; ++r) {
      float2 xv = x2[(size_t)xrow[r] * 64 + i2];
      float2 hv = h2[(size_t)(row0 + r) * 64 + i2];
      air[r] += xv.x * w0a + xv.y * w1a;
      aiz[r] += xv.x * w0b + xv.y * w1b;
      ain[r] += xv.x * w0c + xv.y * w1c;
      ahr[r] += hv.x * v0a + hv.y * v1a;
      ahz[r] += hv.x * v0b + hv.y * v1b;
      ahn[r] += hv.x * v0c + hv.y * v1c;
    }
  }

  __syncthreads();   // all waves finish reading hg before any wave writes it

#pragma unroll
  for (int r = 0; r < ROWS; ++r) {
    float rr = 1.f / (1.f + expf(-(air[r] + ahr[r])));
    float zz = 1.f / (1.f + expf(-(aiz[r] + ahz[r])));
    float nn = tanhf(ain[r] + rr * ahn[r]);
    float hold = hg[(size_t)(row0 + r) * Hdim + j];
    hg[(size_t)(row0 + r) * Hdim + j] = (1.f - zz) * nn + zz * hold;
  }
}

// ---------------- head: out[row] = dot(h[row], head_w) + head_b -------------
__global__ __launch_bounds__(128) void head_kernel(
    const float* __restrict__ hg, const float* __restrict__ hw,
    const float* __restrict__ hb, float* __restrict__ out)
{
  int row = blockIdx.x;
  int j = threadIdx.x;
  __shared__ float red[2];
  float v = hg[(size_t)row * Hdim + j] * hw[j];
#pragma unroll
  for (int off = 32; off >= 1; off >>= 1) v += __shfl_xor(v, off);
  int wid = j >> 6, lane = j & 63;
  if (lane == 0) red[wid] = v;
  __syncthreads();
  if (j == 0) out[row] = red[0] + red[1] + hb[0];
}

extern "C" void kernel_launch(void* const* d_in, const int* in_sizes, int n_in,
                              void* d_out, int out_size, void* d_ws, size_t ws_size,
                              hipStream_t stream)
{
  const float* xseq  = (const float*)d_in[0];
  const int*   ei    = (const int*)d_in[1];
  const float* attr  = (const float*)d_in[2];
  const float* enc_w = (const float*)d_in[3];
  const float* enc_b = (const float*)d_in[4];
  const float* eW    = (const float*)d_in[5];
  const float* eb    = (const float*)d_in[6];
  const float* m1w   = (const float*)d_in[7];
  const float* m1b   = (const float*)d_in[8];
  const float* m2w   = (const float*)d_in[9];
  const float* m2b   = (const float*)d_in[10];
  const float* lng   = (const float*)d_in[11];
  const float* lnb   = (const float*)d_in[12];
  const float* wih   = (const float*)d_in[13];
  const float* whh   = (const float*)d_in[14];
  const float* bih   = (const float*)d_in[15];
  const float* bhh   = (const float*)d_in[16];
  const float* hw    = (const float*)d_in[17];
  const float* hb    = (const float*)d_in[18];

  int E = in_sizes[1] / 2;
  int N = in_sizes[0] / (Bdim * Tdim * Fdim);
  int rowsState = Bdim * N;                    // 20000
  int rowsC = TC * Bdim * N;                   // 80000
  size_t SC = (size_t)rowsC * Hdim;            // chunk buffer floats
  size_t SS = (size_t)rowsState * Hdim;        // state buffer floats

  float* x    = (float*)d_ws;
  float* agg  = x + SC;
  float* hgb  = agg + SC;
  int*   cnt  = (int*)(hgb + SS);
  int*   off  = cnt + N;
  int*   eids = off + (N + 1);
  int*   src_csr = eids + E;
  float* attr_csr = (float*)(src_csr + E);     // [E][16] fp32

  hipMemsetAsync(hgb, 0, SS * sizeof(float), stream);
  hipMemsetAsync(cnt, 0, N * sizeof(int), stream);

  int eBlocks    = (E + 255) / 256;
  int encBlocks  = (rowsC * 32 + 255) / 256;   // 10000
  int mlpBlocks  = rowsC / 16;                 // 5000
  int gruBlocks  = rowsState / 16;             // 1250
  int pullBlocks = (N + 3) / 4;                // 2500
  int reoBlocks  = (E * 4 + 255) / 256;        // 5000

  count_kernel<<<eBlocks, 256, 0, stream>>>(ei, cnt, E);
  scan_kernel<<<1, 1024, 0, stream>>>(cnt, off, N);
  fill_kernel<<<eBlocks, 256, 0, stream>>>(ei, off, eids, src_csr, E);
  reorder_kernel<<<reoBlocks, 256, 0, stream>>>(attr, eids, attr_csr, E);

  for (int c = 0; c < Tdim / TC; ++c) {
    enc_kernel<<<encBlocks, 256, 0, stream>>>(xseq, enc_w, enc_b, x, N, c * TC);
    for (int l = 0; l < 2; ++l) {
      pull_kernel<<<pullBlocks, 256, 0, stream>>>(
          x, agg, src_csr, off, attr_csr,
          eW + (size_t)l * Ddim * Hdim, eb + (size_t)l * Hdim, N);
      mlp_ln_kernel<<<mlpBlocks, 128, 0, stream>>>(
          x, agg, m1w + (size_t)l * Hdim * Hdim, m1b + (size_t)l * Hdim,
          m2w + (size_t)l * Hdim * Hdim, m2b + (size_t)l * Hdim,
          lng + (size_t)l * Hdim, lnb + (size_t)l * Hdim);
    }
    for (int tin = 0; tin < TC; ++tin)
      gru_kernel<<<gruBlocks, 128, 0, stream>>>(x, hgb, wih, whh, bih, bhh, N, tin);
  }
  head_kernel<<<rowsState, 128, 0, stream>>>(hgb, hw, hb, (float*)d_out);
}